// Round 7
// baseline (275.885 us; speedup 1.0000x reference)
//
#include <hip/hip_runtime.h>
#include <cstdint>

#define B_ 4
#define S_ 4096
#define D_ 512
#define M_ (B_*S_)   // 16384 rows

typedef _Float16 f16;
typedef _Float16 f16x8 __attribute__((ext_vector_type(8)));
typedef _Float16 f16x2 __attribute__((ext_vector_type(2)));
typedef float    f32x4 __attribute__((ext_vector_type(4)));

typedef __attribute__((address_space(1))) void* as1p;
typedef __attribute__((address_space(3))) void* as3p;

__device__ __forceinline__ void gl2lds16(const void* g, void* l) {
    __builtin_amdgcn_global_load_lds((as1p)g, (as3p)l, 16, 0, 0);
}

union f16pack { f16x8 v8; f16x2 v2[4]; };

// ---------------- weight prep: v<64: Wv transpose tile; v in 64..127: Wl f16 cast ----------------
__device__ __forceinline__ void weight_job(int v, int t, char* SMEM,
    const float* __restrict__ Wv, const float* __restrict__ Wl,
    f16* __restrict__ WvT, f16* __restrict__ WlH)
{
    const int z = v >> 6, tile_id = v & 63;
    if (z == 1) {    // Wl cast (row-major f16)
        const size_t base = (size_t)tile_id*4096 + (size_t)t*16;
        const float4* s4 = (const float4*)(Wl + base);
        float4 a0 = s4[0], a1 = s4[1], a2 = s4[2], a3 = s4[3];
        f16x8 o0, o1;
        o0[0]=(f16)a0.x; o0[1]=(f16)a0.y; o0[2]=(f16)a0.z; o0[3]=(f16)a0.w;
        o0[4]=(f16)a1.x; o0[5]=(f16)a1.y; o0[6]=(f16)a1.z; o0[7]=(f16)a1.w;
        o1[0]=(f16)a2.x; o1[1]=(f16)a2.y; o1[2]=(f16)a2.z; o1[3]=(f16)a2.w;
        o1[4]=(f16)a3.x; o1[5]=(f16)a3.y; o1[6]=(f16)a3.z; o1[7]=(f16)a3.w;
        *(f16x8*)(WlH + base)     = o0;
        *(f16x8*)(WlH + base + 8) = o1;
        return;
    }
    // Wv transpose tile -> WvT[j][i] = Wv[i][j]
    float (*tile)[68] = (float(*)[68])SMEM;
    const int bx = tile_id & 7, by = tile_id >> 3;
    const int i0 = bx*64, j0 = by*64;
    const int r = t >> 2, cpart = (t & 3)*16;
    {
        const float4* s4 = (const float4*)(Wv + (size_t)(i0 + r)*512 + j0 + cpart);
        float4 a0 = s4[0], a1 = s4[1], a2 = s4[2], a3 = s4[3];
        *(float4*)&tile[r][cpart]    = a0;
        *(float4*)&tile[r][cpart+4]  = a1;
        *(float4*)&tile[r][cpart+8]  = a2;
        *(float4*)&tile[r][cpart+12] = a3;
    }
    __syncthreads();
    const int c = t >> 2, rpart = (t & 3)*16;
    f16x8 o0, o1;
    #pragma unroll
    for (int q = 0; q < 8; q++) o0[q] = (f16)tile[rpart + q][c];
    #pragma unroll
    for (int q = 0; q < 8; q++) o1[q] = (f16)tile[rpart + 8 + q][c];
    *(f16x8*)(WvT + (size_t)(j0 + c)*512 + i0 + rpart)     = o0;
    *(f16x8*)(WvT + (size_t)(j0 + c)*512 + i0 + rpart + 8) = o1;
}

// ---------------- kA: weight prep (0..127) || xs cast + per-block colsum partials (128..383) ----------------
__global__ __launch_bounds__(256) void kA_kernel(
    const float* __restrict__ xs,
    const float* __restrict__ Wv, const float* __restrict__ Wl,
    f16* __restrict__ xs_h, float* __restrict__ xpart,
    f16* __restrict__ WvT, f16* __restrict__ WlH)
{
    __shared__ __attribute__((aligned(16))) char SMEM[17408];
    const int blk = blockIdx.x, t = threadIdx.x;
    if (blk < 128) { weight_job(blk, t, SMEM, Wv, Wl, WvT, WlH); return; }
    const int j = blk - 128;                 // 0..255, 64 rows each
    float* red = (float*)SMEM;               // [4][512]
    const int w = t >> 6, l = t & 63;
    const int col = l * 8;
    float acc[8] = {0,0,0,0,0,0,0,0};
    for (int c = 0; c < 16; c++) {
        int row = j*64 + c*4 + w;
        const float4* p = (const float4*)(xs + (size_t)row*512 + col);
        float4 a = p[0], b = p[1];
        f16x8 o;
        o[0]=(f16)a.x; o[1]=(f16)a.y; o[2]=(f16)a.z; o[3]=(f16)a.w;
        o[4]=(f16)b.x; o[5]=(f16)b.y; o[6]=(f16)b.z; o[7]=(f16)b.w;
        *(f16x8*)(xs_h + (size_t)row*512 + col) = o;
        acc[0]+=a.x; acc[1]+=a.y; acc[2]+=a.z; acc[3]+=a.w;
        acc[4]+=b.x; acc[5]+=b.y; acc[6]+=b.z; acc[7]+=b.w;
    }
    #pragma unroll
    for (int q = 0; q < 8; q++) red[w*512 + col + q] = acc[q];
    __syncthreads();
    #pragma unroll
    for (int k = 0; k < 2; k++) {
        int c = t + k*256;
        xpart[(size_t)j*512 + c] = red[c] + red[512+c] + red[1024+c] + red[1536+c];
    }
}

// ---------------- chain block (one block = one batch, 256 threads):
//  s = reduce 64 partial rows; [S0 = reduce s0vec];
//  g[d] = rowW[d,:]·s + sbias*rbias[d]; outc = Σ g·cdot; h[j] = Σ_d colW[d][j]·g[d] ----------------
__device__ __forceinline__ void chain_block(int b, int t,
    float* sv, float* g1, float* hws,        // LDS: 512 | 512 | 2048 floats
    const float* __restrict__ part,
    const float* __restrict__ s0vec, float* __restrict__ S0out,
    const float* __restrict__ rowW, const float* __restrict__ colW,
    const float* __restrict__ rbias, const float* __restrict__ cdot,
    float sbias_const,
    float* __restrict__ outc,
    float* __restrict__ houtf, f16* __restrict__ houth)
{
    const int l = t & 63, w = t >> 6, p = l & 15;
    const int g4 = l >> 4;
    // step 1: column-sum of 64 partial rows -> sv  (2 cols/thread, 64 plain loads)
    {
        float a0 = 0.f, a1 = 0.f;
        const float* base = part + (size_t)(b*64)*512 + 2*t;
        #pragma unroll 8
        for (int r = 0; r < 64; r++) {
            float2 v = *(const float2*)(base + (size_t)r*512);
            a0 += v.x; a1 += v.y;
        }
        sv[2*t] = a0; sv[2*t+1] = a1;
    }
    float sbias = sbias_const;
    __syncthreads();
    if (s0vec) {  // S0 = Σ_{r<64} s0vec[b*64+r]
        if (t < 64) {
            float s0 = s0vec[b*64 + t];
            #pragma unroll
            for (int m = 1; m < 64; m <<= 1) s0 += __shfl_xor(s0, m);
            if (t == 0) { hws[0] = s0; *S0out = s0; }
        }
        __syncthreads();
        sbias = hws[0];
        __syncthreads();
    }
    // step 2: g1[d] = rowW[d,:]·s + sbias*rbias[d]   (16 lanes per row, coalesced)
    float vs[32];
    #pragma unroll
    for (int c = 0; c < 32; c++) vs[c] = sv[p*32 + c];
    for (int it = 0; it < 32; it++) {
        const int r = w*128 + it*4 + g4;
        const float4* wr = (const float4*)(rowW + (size_t)r*512 + p*32);
        float acc = 0.f;
        #pragma unroll
        for (int u4 = 0; u4 < 8; u4++) {
            float4 a = wr[u4];
            acc += a.x*vs[u4*4] + a.y*vs[u4*4+1] + a.z*vs[u4*4+2] + a.w*vs[u4*4+3];
        }
        acc += __shfl_xor(acc, 1);
        acc += __shfl_xor(acc, 2);
        acc += __shfl_xor(acc, 4);
        acc += __shfl_xor(acc, 8);
        if (p == 0) g1[r] = acc + sbias * rbias[r];
    }
    __syncthreads();
    // step 3: outc = Σ g1·cdot   (LDS tree in hws scratch)
    {
        float cacc = g1[t]*cdot[t] + g1[t+256]*cdot[t+256];
        hws[t] = cacc;
        __syncthreads();
        if (t < 128) hws[t] += hws[t+128];
        __syncthreads();
        if (t < 64) {
            float s = hws[t] + hws[t+64];
            #pragma unroll
            for (int m = 1; m < 64; m <<= 1) s += __shfl_xor(s, m);
            if (t == 0) *outc = s;
        }
        __syncthreads();
    }
    // step 4: h[j] = Σ_d colW[d][j]·g1[d]  (in-register 32-col accumulators, coalesced)
    float hacc[32];
    #pragma unroll
    for (int c = 0; c < 32; c++) hacc[c] = 0.f;
    for (int it = 0; it < 32; it++) {
        const int r = w*128 + it*4 + g4;
        const float gr = g1[r];
        const float4* wq = (const float4*)(colW + (size_t)r*512 + p*32);
        #pragma unroll
        for (int u4 = 0; u4 < 8; u4++) {
            float4 a = wq[u4];
            hacc[u4*4]   += gr*a.x;
            hacc[u4*4+1] += gr*a.y;
            hacc[u4*4+2] += gr*a.z;
            hacc[u4*4+3] += gr*a.w;
        }
    }
    #pragma unroll
    for (int c = 0; c < 32; c++) {
        hacc[c] += __shfl_xor(hacc[c], 16);   // reduce over g4 groups (same p)
        hacc[c] += __shfl_xor(hacc[c], 32);
    }
    if (g4 == 0) {
        #pragma unroll
        for (int c = 0; c < 32; c++) hws[w*512 + p*32 + c] = hacc[c];
    }
    __syncthreads();
    {
        float h0 = hws[t]     + hws[512+t]     + hws[1024+t]     + hws[1536+t];
        float h1 = hws[t+256] + hws[512+t+256] + hws[1024+t+256] + hws[1536+t+256];
        if (houtf) { houtf[t] = h0; houtf[t+256] = h1; }
        if (houth) { houth[t] = (f16)h0; houth[t+256] = (f16)h1; }
    }
}

// ---------------- Wvl GEMM job (v = 0..63): WvlH = WlH @ WvT^T, + bvl ----------------
__device__ __forceinline__ void wvl_job(int v, int t, char* SMEM,
    const f16* __restrict__ WlH, const f16* __restrict__ WvT,
    const float* __restrict__ Wl, const float* __restrict__ bv,
    f16* __restrict__ WvlH, float* __restrict__ bvlG)
{
    f16* lA = (f16*)SMEM;          // 4KB
    f16* lB = lA + 64*32;          // 4KB
    const int bx = v & 7, by = v >> 3;
    const int i0 = bx*64, j0 = by*64;
    const int lane = t & 63, wid = t >> 6;
    const int wm = (wid & 1)*32, wn = (wid >> 1)*32;
    const int srow = t >> 2, skb = (t & 3) << 4;
    const long aoff = (long)(i0 + srow)*1024 + skb;
    const long boff = (long)(j0 + srow)*1024 + skb;
    const unsigned wbase = (unsigned)wid << 10;
    f32x4 acc[2][2] = {};
    const int ael = (wm + (lane & 15))*32 + ((lane >> 4) << 3);
    const int bel = (wn + (lane & 15))*32 + ((lane >> 4) << 3);
    for (int k0 = 0; k0 < 512; k0 += 32) {
        __syncthreads();
        gl2lds16((const char*)WlH + aoff + k0*2, (char*)lA + wbase);
        gl2lds16((const char*)WvT + boff + k0*2, (char*)lB + wbase);
        __syncthreads();
        f16x8 af[2], bf[2];
        af[0] = *(const f16x8*)(lA + ael);
        af[1] = *(const f16x8*)(lA + ael + 512);
        bf[0] = *(const f16x8*)(lB + bel);
        bf[1] = *(const f16x8*)(lB + bel + 512);
        #pragma unroll
        for (int i = 0; i < 2; i++)
            #pragma unroll
            for (int j = 0; j < 2; j++)
                acc[i][j] = __builtin_amdgcn_mfma_f32_16x16x32_f16(af[i], bf[j], acc[i][j], 0, 0, 0);
    }
    const int rb = wm + ((lane >> 4) << 2);
    const int cb = wn + (lane & 15);
    #pragma unroll
    for (int i = 0; i < 2; i++)
        #pragma unroll
        for (int j = 0; j < 2; j++)
            #pragma unroll
            for (int r = 0; r < 4; r++)
                WvlH[(size_t)(i0 + rb + i*16 + r)*512 + j0 + cb + j*16] = (f16)acc[i][j][r];
    if (by == 0) {
        int r = t >> 2, part = t & 3;
        const float4* wr = (const float4*)(Wl + (size_t)(i0+r)*512 + part*128);
        const float4* bp = (const float4*)(bv + part*128);
        float s = 0.f;
        #pragma unroll 8
        for (int q = 0; q < 32; q++) {
            float4 wv4 = wr[q], b4 = bp[q];
            s += wv4.x*b4.x + wv4.y*b4.y + wv4.z*b4.z + wv4.w*b4.w;
        }
        s += __shfl_xor(s, 1);
        s += __shfl_xor(s, 2);
        if (part == 0) bvlG[i0 + r] = s;
    }
}

// ---------------- kC: Wvl GEMM (0..63) || h-chain (64..67, one block per batch) ----------------
__global__ __launch_bounds__(256) void kC_kernel(
    const f16* __restrict__ WlH, const f16* __restrict__ WvT,
    const float* __restrict__ Wl, const float* __restrict__ bv,
    f16* __restrict__ WvlH, float* __restrict__ bvlG,
    const float* __restrict__ xpart,
    const float* __restrict__ Wk, const float* __restrict__ Wq,
    const float* __restrict__ bk, const float* __restrict__ bq,
    float* __restrict__ hG, float* __restrict__ c1G)
{
    __shared__ __attribute__((aligned(16))) float SMEMF[3072];  // 12 KB
    const int blk = blockIdx.x, t = threadIdx.x;
    if (blk < 64) { wvl_job(blk, t, (char*)SMEMF, WlH, WvT, Wl, bv, WvlH, bvlG); return; }
    const int b = blk - 64;
    // g1 = Wk@s + 4096*bk ; c1 = bq·g1 ; hG[b] = Wq^T g1
    chain_block(b, t, SMEMF, SMEMF + 512, SMEMF + 1024, xpart, nullptr, nullptr,
                Wk, Wq, bk, bq, 4096.0f, c1G + b, hG + (size_t)b*512, nullptr);
}

// ---------------- kD: z pass (256 blocks, 64 rows each): iv = 1/(4096+(xs·h+c1)/512) ----------------
__global__ __launch_bounds__(256) void kD_kernel(
    const f16* __restrict__ xs_h, const float* __restrict__ hG,
    const float* __restrict__ c1G,
    float* __restrict__ zpart, float* __restrict__ s0part)
{
    __shared__ __attribute__((aligned(16))) float SMEMF[2564];  // hs 512 | yred 2048 | s0red 4
    float* hs    = SMEMF;
    float* yred  = hs + 512;
    float* s0red = yred + 2048;
    const int z = blockIdx.x, t = threadIdx.x;
    const int b = z >> 6, w = t >> 6, l = t & 63;
    hs[t] = hG[(size_t)b*512 + t]; hs[t+256] = hG[(size_t)b*512 + t + 256];
    __syncthreads();
    const float c1 = c1G[b];
    float hx[8];
    #pragma unroll
    for (int q = 0; q < 8; q++) hx[q] = hs[l*8+q];
    float yacc[8] = {0,0,0,0,0,0,0,0};
    float s0acc = 0.f;
    for (int it = 0; it < 16; it++) {
        int row = z*64 + w*16 + it;
        f16x8 v = *(const f16x8*)(xs_h + (size_t)row*512 + l*8);
        float xf[8];
        #pragma unroll
        for (int q = 0; q < 8; q++) xf[q] = (float)v[q];
        float d = 0.f;
        #pragma unroll
        for (int q = 0; q < 8; q++) d += xf[q]*hx[q];
        #pragma unroll
        for (int m = 1; m < 64; m <<= 1) d += __shfl_xor(d, m);
        float zz = 4096.0f + (d + c1)*(1.0f/512.0f);
        float iv = 1.0f/zz;
        s0acc += iv;
        #pragma unroll
        for (int q = 0; q < 8; q++) yacc[q] += iv*xf[q];
    }
    #pragma unroll
    for (int q = 0; q < 8; q++) yred[w*512 + l*8+q] = yacc[q];
    if (l == 0) s0red[w] = s0acc;
    __syncthreads();
    #pragma unroll
    for (int k = 0; k < 2; k++) {
        int c = t + k*256;
        zpart[(size_t)z*512 + c] = yred[c]+yred[512+c]+yred[1024+c]+yred[1536+c];
    }
    if (t == 0) s0part[z] = s0red[0]+s0red[1]+s0red[2]+s0red[3];
}

// ---------------- kF: u-chain (4 blocks, one per batch) ----------------
__global__ __launch_bounds__(256) void kF_kernel(
    const float* __restrict__ zpart, const float* __restrict__ s0part,
    const float* __restrict__ Wq, const float* __restrict__ Wk,
    const float* __restrict__ bq, const float* __restrict__ bk,
    float* __restrict__ S0G, float* __restrict__ c2G, f16* __restrict__ uH)
{
    __shared__ __attribute__((aligned(16))) float SMEMF[3072];
    const int b = blockIdx.x, t = threadIdx.x;
    // S0 = Σ s0part ; g2 = Wq@y + S0*bq ; c2 = bk·g2 ; uH[b] = (f16)(Wk^T g2)
    chain_block(b, t, SMEMF, SMEMF + 512, SMEMF + 1024, zpart, s0part, S0G + b,
                Wq, Wk, bq, bk, 0.0f, c2G + b, nullptr, uH + (size_t)b*512);
}

// ---------------- kG: vl_gemm: out = tanh(rs*(xs@Wvl^T + bvl) + bl), rs fused via v_dot2 ----------------
__global__ __launch_bounds__(256, 2) void vl_gemm(const f16* __restrict__ A,
    const f16* __restrict__ Bt, const float* __restrict__ bvlG,
    const float* __restrict__ blG, const f16* __restrict__ uH,
    const float* __restrict__ c2G, const float* __restrict__ S0G,
    float* __restrict__ out)
{
    constexpr int K = 512;
    __shared__ f16 lA[128*32];
    __shared__ f16 lB[128*32];
    __shared__ float rsbuf[128];
    const int t = threadIdx.x;
    const int m0 = blockIdx.x*128, n0 = blockIdx.y*128;
    const int lane = t & 63, wid = t >> 6;
    const int wm = (wid & 1) << 6, wn = (wid >> 1) << 6;
    const int srow = t >> 2, skb = (t & 3) << 4;
    const long aoff0 = (long)(m0 + srow)*(K*2) + skb;
    const long aoff1 = aoff0 + 64L*(K*2);
    const long boff0 = (long)(n0 + srow)*(K*2) + skb;
    const long boff1 = boff0 + 64L*(K*2);
    char* ldsA = (char*)lA;
    char* ldsB = (char*)lB;
    const unsigned wbase = (unsigned)wid << 10;
    const char* Ab = (const char*)A;
    const char* Bb = (const char*)Bt;

    const int bat = blockIdx.x >> 5;          // 32 m-tiles per batch
    const f16* u = uH + bat*512;
    const int ku = (lane >> 4) << 3;

    f32x4 acc[4][4] = {};
    float racc[4] = {0.f,0.f,0.f,0.f};
    const int ael = (wm + (lane & 15))*32 + ku;
    const int bel = (wn + (lane & 15))*32 + ku;

    for (int k0 = 0; k0 < K; k0 += 32) {
        __syncthreads();
        const long kb = (long)k0*2;
        gl2lds16(Ab + aoff0 + kb, ldsA + wbase);
        gl2lds16(Ab + aoff1 + kb, ldsA + 4096 + wbase);
        gl2lds16(Bb + boff0 + kb, ldsB + wbase);
        gl2lds16(Bb + boff1 + kb, ldsB + 4096 + wbase);
        __syncthreads();
        f16x8 af[4], bf[4];
        #pragma unroll
        for (int i = 0; i < 4; i++) af[i] = *(const f16x8*)(lA + ael + i*512);
        #pragma unroll
        for (int j = 0; j < 4; j++) bf[j] = *(const f16x8*)(lB + bel + j*512);
        f16pack up; up.v8 = *(const f16x8*)(u + k0 + ku);
        #pragma unroll
        for (int i = 0; i < 4; i++) {
            f16pack ap; ap.v8 = af[i];
            #pragma unroll
            for (int q = 0; q < 4; q++)
                racc[i] = __builtin_amdgcn_fdot2(ap.v2[q], up.v2[q], racc[i], false);
        }
        #pragma unroll
        for (int i = 0; i < 4; i++)
            #pragma unroll
            for (int j = 0; j < 4; j++)
                acc[i][j] = __builtin_amdgcn_mfma_f32_16x16x32_f16(af[i], bf[j], acc[i][j], 0, 0, 0);
    }

    #pragma unroll
    for (int i = 0; i < 4; i++) {
        racc[i] += __shfl_xor(racc[i], 16);
        racc[i] += __shfl_xor(racc[i], 32);
    }
    const float S0 = S0G[bat], c2 = c2G[bat];
    if (wid < 2 && lane < 16) {
        #pragma unroll
        for (int i = 0; i < 4; i++)
            rsbuf[wm + i*16 + lane] = S0 + (racc[i] + c2)*(1.0f/512.0f);
    }
    __syncthreads();

    const int crb = m0 + wm + ((lane >> 4) << 2);
    const int ccb = n0 + wn + (lane & 15);
    const int lrb = wm + ((lane >> 4) << 2);
    #pragma unroll
    for (int i = 0; i < 4; i++) {
        float rsv[4];
        #pragma unroll
        for (int r = 0; r < 4; r++) rsv[r] = rsbuf[lrb + i*16 + r];
        #pragma unroll
        for (int j = 0; j < 4; j++) {
            int c = ccb + j*16;
            float bb = bvlG[c], bo = blG[c];
            #pragma unroll
            for (int r = 0; r < 4; r++) {
                float yv = rsv[r]*(acc[i][j][r] + bb) + bo;
                float e2 = __expf(2.0f*yv);
                out[(size_t)(crb + i*16 + r)*512 + c] = 1.0f - 2.0f/(e2 + 1.0f);
            }
        }
    }
}

extern "C" void kernel_launch(void* const* d_in, const int* in_sizes, int n_in,
                              void* d_out, int out_size, void* d_ws, size_t ws_size,
                              hipStream_t stream)
{
    const float* xs = (const float*)d_in[0];
    const float* Wk = (const float*)d_in[1];
    const float* bk = (const float*)d_in[2];
    const float* Wq = (const float*)d_in[3];
    const float* bq = (const float*)d_in[4];
    const float* Wv = (const float*)d_in[5];
    const float* bv = (const float*)d_in[6];
    const float* Wl = (const float*)d_in[7];
    const float* bl = (const float*)d_in[8];
    float* out = (float*)d_out;

    char* w = (char*)d_ws;
    f16*   xs_h = (f16*)w;   w += (size_t)M_*D_*2;   // 16.8 MB
    f16*   WvlH = (f16*)w;   w += (size_t)D_*D_*2;
    f16*   WlH  = (f16*)w;   w += (size_t)D_*D_*2;
    f16*   WvT  = (f16*)w;   w += (size_t)D_*D_*2;
    f16*   uH   = (f16*)w;   w += (size_t)B_*D_*2;
    float* bvlG = (float*)w; w += (size_t)D_*4;
    float* xpart= (float*)w; w += (size_t)256*512*4;   // 512 KB
    float* zpart= (float*)w; w += (size_t)256*512*4;   // 512 KB
    float* s0part=(float*)w; w += (size_t)256*4;
    float* hG   = (float*)w; w += (size_t)B_*D_*4;
    float* c1G  = (float*)w; w += B_*4;
    float* c2G  = (float*)w; w += B_*4;
    float* S0G  = (float*)w; w += B_*4;
    if ((size_t)(w - (char*)d_ws) > ws_size) return;  // fail loudly

    // no memset needed: no atomics, every buffer fully written by its producer

    kA_kernel<<<384, 256, 0, stream>>>(xs, Wv, Wl, xs_h, xpart, WvT, WlH);

    kC_kernel<<<68, 256, 0, stream>>>(WlH, WvT, Wl, bv, WvlH, bvlG,
        xpart, Wk, Wq, bk, bq, hG, c1G);

    kD_kernel<<<256, 256, 0, stream>>>(xs_h, hG, c1G, zpart, s0part);

    kF_kernel<<<4, 256, 0, stream>>>(zpart, s0part, Wq, Wk, bq, bk, S0G, c2G, uH);

    vl_gemm<<<dim3(128,4), 256, 0, stream>>>(xs_h, WvlH, bvlG, bl, uH, c2G, S0G, out);
}

// Round 8
// 154.265 us; speedup vs baseline: 1.7884x; 1.7884x over previous
//
#include <hip/hip_runtime.h>
#include <cstdint>

#define B_ 4
#define S_ 4096
#define D_ 512
#define M_ (B_*S_)   // 16384 rows

typedef _Float16 f16;
typedef _Float16 f16x8 __attribute__((ext_vector_type(8)));
typedef _Float16 f16x2 __attribute__((ext_vector_type(2)));
typedef float    f32x4 __attribute__((ext_vector_type(4)));

typedef __attribute__((address_space(1))) void* as1p;
typedef __attribute__((address_space(3))) void* as3p;

__device__ __forceinline__ void gl2lds16(const void* g, void* l) {
    __builtin_amdgcn_global_load_lds((as1p)g, (as3p)l, 16, 0, 0);
}

union f16pack { f16x8 v8; f16x2 v2[4]; };

// ---------------- prep_tr: blocks 0..255 = xs cast + per-block column partials into xpart;
//                  blocks 256..511 = weight transpose/cast to f16 (no atomics) ----------------
__global__ __launch_bounds__(256) void prep_tr_kernel(
    const float* __restrict__ xs,
    const float* __restrict__ Wv, const float* __restrict__ Wk,
    const float* __restrict__ Wq, const float* __restrict__ Wl,
    f16* __restrict__ xs_h, float* __restrict__ xpart,
    f16* __restrict__ WvT, f16* __restrict__ WkT, f16* __restrict__ WqT,
    f16* __restrict__ WlH)
{
    __shared__ float smem[64*68];   // prep: red[4][512] (8KB); tr: tile[64][68] (17.4KB)
    const int t = threadIdx.x;
    if (blockIdx.x < 256) {
        const int blk = blockIdx.x;
        const int w = t >> 6, l = t & 63;
        const int col = l * 8;
        float acc[8] = {0,0,0,0,0,0,0,0};
        for (int c = 0; c < 16; c++) {
            int row = blk*64 + c*4 + w;
            const float4* p = (const float4*)(xs + (size_t)row*512 + col);
            float4 a = p[0], b = p[1];
            f16x8 o;
            o[0]=(f16)a.x; o[1]=(f16)a.y; o[2]=(f16)a.z; o[3]=(f16)a.w;
            o[4]=(f16)b.x; o[5]=(f16)b.y; o[6]=(f16)b.z; o[7]=(f16)b.w;
            *(f16x8*)(xs_h + (size_t)row*512 + col) = o;
            acc[0]+=a.x; acc[1]+=a.y; acc[2]+=a.z; acc[3]+=a.w;
            acc[4]+=b.x; acc[5]+=b.y; acc[6]+=b.z; acc[7]+=b.w;
        }
        #pragma unroll
        for (int q = 0; q < 8; q++) smem[w*512 + col + q] = acc[q];
        __syncthreads();
        #pragma unroll
        for (int k = 0; k < 2; k++) {
            int c = t + k*256;
            xpart[(size_t)blk*512 + c] = smem[c] + smem[512+c] + smem[1024+c] + smem[1536+c];
        }
        return;
    }
    const int v = blockIdx.x - 256;
    const int z = v >> 6, tile_id = v & 63;
    const int bx = tile_id & 7, by = tile_id >> 3;
    if (z == 3) {    // Wl cast (row-major f16)
        const size_t base = (size_t)tile_id*4096 + (size_t)t*16;
        const float4* s4 = (const float4*)(Wl + base);
        float4 a0 = s4[0], a1 = s4[1], a2 = s4[2], a3 = s4[3];
        f16x8 o0, o1;
        o0[0]=(f16)a0.x; o0[1]=(f16)a0.y; o0[2]=(f16)a0.z; o0[3]=(f16)a0.w;
        o0[4]=(f16)a1.x; o0[5]=(f16)a1.y; o0[6]=(f16)a1.z; o0[7]=(f16)a1.w;
        o1[0]=(f16)a2.x; o1[1]=(f16)a2.y; o1[2]=(f16)a2.z; o1[3]=(f16)a2.w;
        o1[4]=(f16)a3.x; o1[5]=(f16)a3.y; o1[6]=(f16)a3.z; o1[7]=(f16)a3.w;
        *(f16x8*)(WlH + base)     = o0;
        *(f16x8*)(WlH + base + 8) = o1;
        return;
    }
    // transpose tile (row stride 68 floats -> float4 stores at {0,64,128,192} aligned)
    float (*tile)[68] = (float(*)[68])smem;
    const float* src = (z == 0) ? Wv : ((z == 1) ? Wk : Wq);
    f16* dst = (z == 0) ? WvT : ((z == 1) ? WkT : WqT);
    const int i0 = bx*64, j0 = by*64;
    const int r = t >> 2, cpart = (t & 3)*16;
    {
        const float4* s4 = (const float4*)(src + (size_t)(i0 + r)*512 + j0 + cpart);
        float4 a0 = s4[0], a1 = s4[1], a2 = s4[2], a3 = s4[3];
        *(float4*)&tile[r][cpart]    = a0;
        *(float4*)&tile[r][cpart+4]  = a1;
        *(float4*)&tile[r][cpart+8]  = a2;
        *(float4*)&tile[r][cpart+12] = a3;
    }
    __syncthreads();
    const int c = t >> 2, rpart = (t & 3)*16;
    f16x8 o0, o1;
    #pragma unroll
    for (int q = 0; q < 8; q++) o0[q] = (f16)tile[rpart + q][c];
    #pragma unroll
    for (int q = 0; q < 8; q++) o1[q] = (f16)tile[rpart + 8 + q][c];
    *(f16x8*)(dst + (size_t)(j0 + c)*512 + i0 + rpart)     = o0;
    *(f16x8*)(dst + (size_t)(j0 + c)*512 + i0 + rpart + 8) = o1;
}

// ---------------- wide partial reduce: block (b, sl) sums 64 partial rows over cols [sl*32, sl*32+32) ----------------
__device__ __forceinline__ void reduce_slice(int b, int sl, int t, float* redf,
    const float* __restrict__ part, float* __restrict__ outv)
{
    const int col = sl*32 + (t & 31), rg = t >> 5;   // 8 row-groups x 32 cols
    float s = 0.f;
    #pragma unroll
    for (int r = 0; r < 8; r++)
        s += part[(size_t)(b*64 + rg*8 + r)*512 + col];
    redf[rg*32 + (t & 31)] = s;
    __syncthreads();
    if (t < 32) {
        float v = 0.f;
        #pragma unroll
        for (int g = 0; g < 8; g++) v += redf[g*32 + t];
        outv[b*512 + sl*32 + t] = v;
    }
}

// ---------------- wmm: MFMA weight GEMMs (z 0..2) + xsSum reduce (z==3) ----------------
// z==0: Wvl = WlH @ WvT^T (f16 out); y==0: bvl = Wl@bv
// z==1: Mm[j][e] = sum_d Wk[d][j]*Wq[d][e]; x==0: t1; y==0: t2; (0,0): t12
// z==2: MT[e][j]; z==3: xsSum = reduce(xpart)
__global__ __launch_bounds__(256) void wmm_kernel(
    const f16* __restrict__ WlH, const f16* __restrict__ WvT,
    const f16* __restrict__ WkT, const f16* __restrict__ WqT,
    const float* __restrict__ Wl, const float* __restrict__ bv,
    const float* __restrict__ bk, const float* __restrict__ bq,
    f16* __restrict__ WvlH, float* __restrict__ bvlG,
    float* __restrict__ Mm, float* __restrict__ MT,
    float* __restrict__ t1, float* __restrict__ t2, float* __restrict__ t12,
    const float* __restrict__ xpart, float* __restrict__ xsSum)
{
    __shared__ f16 lA[64*32];
    __shared__ f16 lB[64*32];
    const int t = threadIdx.x, z = blockIdx.z;
    if (z == 3) {
        const int id = blockIdx.y*8 + blockIdx.x;     // 0..63
        reduce_slice(id >> 4, id & 15, t, (float*)lA, xpart, xsSum);
        return;
    }
    const int i0 = blockIdx.x*64, j0 = blockIdx.y*64;
    const int lane = t & 63, wid = t >> 6;
    const int wm = (wid & 1)*32, wn = (wid >> 1)*32;
    const f16* A = (z == 0) ? WlH : ((z == 1) ? WkT : WqT);
    const f16* B = (z == 0) ? WvT : ((z == 1) ? WqT : WkT);
    const int srow = t >> 2, skb = (t & 3) << 4;
    const long aoff = (long)(i0 + srow)*1024 + skb;
    const long boff = (long)(j0 + srow)*1024 + skb;
    const unsigned wbase = (unsigned)wid << 10;
    const bool doT1 = (z == 1) && (blockIdx.x == 0);
    const bool doT2 = (z == 1) && (blockIdx.y == 0);
    const int jj = t >> 2, kq = (t & 3)*8;

    f32x4 acc[2][2] = {};
    float t1a = 0.f, t2a = 0.f;
    const int ael = (wm + (lane & 15))*32 + ((lane >> 4) << 3);
    const int bel = (wn + (lane & 15))*32 + ((lane >> 4) << 3);

    for (int k0 = 0; k0 < 512; k0 += 32) {
        __syncthreads();
        gl2lds16((const char*)A + aoff + k0*2, (char*)lA + wbase);
        gl2lds16((const char*)B + boff + k0*2, (char*)lB + wbase);
        __syncthreads();
        f16x8 af[2], bf[2];
        af[0] = *(const f16x8*)(lA + ael);
        af[1] = *(const f16x8*)(lA + ael + 512);
        bf[0] = *(const f16x8*)(lB + bel);
        bf[1] = *(const f16x8*)(lB + bel + 512);
        #pragma unroll
        for (int i = 0; i < 2; i++)
            #pragma unroll
            for (int j = 0; j < 2; j++)
                acc[i][j] = __builtin_amdgcn_mfma_f32_16x16x32_f16(af[i], bf[j], acc[i][j], 0, 0, 0);
        if (doT1) {
            float4 b0 = *(const float4*)(bk + k0 + kq);
            float4 b1 = *(const float4*)(bk + k0 + kq + 4);
            float bb[8] = {b0.x,b0.y,b0.z,b0.w,b1.x,b1.y,b1.z,b1.w};
            #pragma unroll
            for (int q = 0; q < 8; q++) t1a += (float)lB[jj*32 + kq + q] * bb[q];
        }
        if (doT2) {
            float4 b0 = *(const float4*)(bq + k0 + kq);
            float4 b1 = *(const float4*)(bq + k0 + kq + 4);
            float bb[8] = {b0.x,b0.y,b0.z,b0.w,b1.x,b1.y,b1.z,b1.w};
            #pragma unroll
            for (int q = 0; q < 8; q++) t2a += (float)lA[jj*32 + kq + q] * bb[q];
        }
    }

    const int rb = wm + ((lane >> 4) << 2);
    const int cb = wn + (lane & 15);
    if (z == 0) {
        #pragma unroll
        for (int i = 0; i < 2; i++)
            #pragma unroll
            for (int j = 0; j < 2; j++)
                #pragma unroll
                for (int r = 0; r < 4; r++)
                    WvlH[(size_t)(i0 + rb + i*16 + r)*512 + j0 + cb + j*16] = (f16)acc[i][j][r];
        if (blockIdx.y == 0) {
            int r = t >> 2, part = t & 3;
            const float4* wr = (const float4*)(Wl + (size_t)(i0+r)*512 + part*128);
            const float4* bp = (const float4*)(bv + part*128);
            float s = 0.f;
            #pragma unroll 8
            for (int q = 0; q < 32; q++) {
                float4 wv4 = wr[q], b4 = bp[q];
                s += wv4.x*b4.x + wv4.y*b4.y + wv4.z*b4.z + wv4.w*b4.w;
            }
            s += __shfl_xor(s, 1);
            s += __shfl_xor(s, 2);
            if (part == 0) bvlG[i0 + r] = s;
        }
    } else {
        float* Cout = (z == 1) ? Mm : MT;
        #pragma unroll
        for (int i = 0; i < 2; i++)
            #pragma unroll
            for (int j = 0; j < 2; j++)
                #pragma unroll
                for (int r = 0; r < 4; r++)
                    Cout[(size_t)(i0 + rb + i*16 + r)*512 + j0 + cb + j*16] = acc[i][j][r];
        if (doT1) {
            t1a += __shfl_xor(t1a, 1);
            t1a += __shfl_xor(t1a, 2);
            if ((lane & 3) == 0) t1[j0 + jj] = t1a;
        }
        if (doT2) {
            t2a += __shfl_xor(t2a, 1);
            t2a += __shfl_xor(t2a, 2);
            if ((lane & 3) == 0) t2[i0 + jj] = t2a;
        }
        if (z == 1 && blockIdx.x == 0 && blockIdx.y == 0 && wid == 0) {
            float s = 0.f;
            #pragma unroll
            for (int q = 0; q < 8; q++) s += bk[lane + q*64]*bq[lane + q*64];
            #pragma unroll
            for (int m = 1; m < 64; m <<= 1) s += __shfl_xor(s, m);
            if (lane == 0) *t12 = s;
        }
    }
}

// ---------------- mva: oput[b][j] = W[j,:].vin[b] + beta_b*bias2[j]  (+ f16 copy) ----------------
// block 32: cG[b] = bias3.vin[b] + beta_b * t12
__global__ __launch_bounds__(256) void mva_kernel(const float* __restrict__ W,
    const float* __restrict__ vin, const float* __restrict__ bias2,
    const float* __restrict__ bias3, const float* __restrict__ betaG,
    const float* __restrict__ t12G,
    float* __restrict__ oput, f16* __restrict__ oput_h, float* __restrict__ cG)
{
    const int t = threadIdx.x, w = t >> 6, l = t & 63;
    if (blockIdx.x == 32) {
        const float4* b4 = (const float4*)(bias3 + l*8);
        const float4* v4 = (const float4*)(vin + w*512 + l*8);
        float4 b0 = b4[0], b1 = b4[1], v0 = v4[0], v1 = v4[1];
        float s = b0.x*v0.x + b0.y*v0.y + b0.z*v0.z + b0.w*v0.w
                + b1.x*v1.x + b1.y*v1.y + b1.z*v1.z + b1.w*v1.w;
        #pragma unroll
        for (int m = 1; m < 64; m <<= 1) s += __shfl_xor(s, m);
        if (l == 0) {
            float beta = betaG ? betaG[w] : 4096.0f;
            cG[w] = s + beta * (*t12G);
        }
        return;
    }
    float vb[4][8];
    #pragma unroll
    for (int b = 0; b < 4; b++) {
        float4 p0 = *(const float4*)(vin + b*512 + l*8);
        float4 p1 = *(const float4*)(vin + b*512 + l*8 + 4);
        vb[b][0]=p0.x; vb[b][1]=p0.y; vb[b][2]=p0.z; vb[b][3]=p0.w;
        vb[b][4]=p1.x; vb[b][5]=p1.y; vb[b][6]=p1.z; vb[b][7]=p1.w;
    }
    const int r0 = blockIdx.x*16 + w*4;
    float res[4][4];
    #pragma unroll
    for (int r = 0; r < 4; r++) {
        const float4* wr = (const float4*)(W + (size_t)(r0+r)*512 + l*8);
        float4 a = wr[0], c = wr[1];
        float wv[8] = {a.x,a.y,a.z,a.w,c.x,c.y,c.z,c.w};
        #pragma unroll
        for (int b = 0; b < 4; b++) {
            float s = 0.f;
            #pragma unroll
            for (int q = 0; q < 8; q++) s += wv[q]*vb[b][q];
            res[r][b] = s;
        }
    }
    #pragma unroll
    for (int r = 0; r < 4; r++)
        #pragma unroll
        for (int b = 0; b < 4; b++)
            #pragma unroll
            for (int m = 1; m < 64; m <<= 1) res[r][b] += __shfl_xor(res[r][b], m);
    if (l < 4) {
        const float beta = betaG ? betaG[l] : 4096.0f;
        #pragma unroll
        for (int r = 0; r < 4; r++) {
            float val = res[r][l] + beta*bias2[r0 + r];
            oput[l*512 + r0 + r] = val;
            if (oput_h) oput_h[l*512 + r0 + r] = (f16)val;
        }
    }
}

// ---------------- z pass (256 blocks, 64 rows each): iv = 1/(4096+(xs·h+c1)/512); partials out ----------------
__global__ __launch_bounds__(256) void z_kernel(
    const f16* __restrict__ xs_h, const float* __restrict__ hG,
    const float* __restrict__ c1G,
    float* __restrict__ zpart, float* __restrict__ s0part)
{
    __shared__ __attribute__((aligned(16))) float SMEMF[2564];  // hs 512 | yred 2048 | s0red 4
    float* hs    = SMEMF;
    float* yred  = hs + 512;
    float* s0red = yred + 2048;
    const int z = blockIdx.x, t = threadIdx.x;
    const int b = z >> 6, w = t >> 6, l = t & 63;
    hs[t] = hG[(size_t)b*512 + t]; hs[t+256] = hG[(size_t)b*512 + t + 256];
    __syncthreads();
    const float c1 = c1G[b];
    float hx[8];
    #pragma unroll
    for (int q = 0; q < 8; q++) hx[q] = hs[l*8+q];
    float yacc[8] = {0,0,0,0,0,0,0,0};
    float s0acc = 0.f;
    for (int it = 0; it < 16; it++) {
        int row = z*64 + w*16 + it;
        f16x8 v = *(const f16x8*)(xs_h + (size_t)row*512 + l*8);
        float xf[8];
        #pragma unroll
        for (int q = 0; q < 8; q++) xf[q] = (float)v[q];
        float d = 0.f;
        #pragma unroll
        for (int q = 0; q < 8; q++) d += xf[q]*hx[q];
        #pragma unroll
        for (int m = 1; m < 64; m <<= 1) d += __shfl_xor(d, m);
        float zz = 4096.0f + (d + c1)*(1.0f/512.0f);
        float iv = 1.0f/zz;
        s0acc += iv;
        #pragma unroll
        for (int q = 0; q < 8; q++) yacc[q] += iv*xf[q];
    }
    #pragma unroll
    for (int q = 0; q < 8; q++) yred[w*512 + l*8+q] = yacc[q];
    if (l == 0) s0red[w] = s0acc;
    __syncthreads();
    #pragma unroll
    for (int k = 0; k < 2; k++) {
        int c = t + k*256;
        zpart[(size_t)z*512 + c] = yred[c]+yred[512+c]+yred[1024+c]+yred[1536+c];
    }
    if (t == 0) s0part[z] = s0red[0]+s0red[1]+s0red[2]+s0red[3];
}

// ---------------- red: yG = reduce(zpart) over 64 blocks; S0G from s0part ----------------
__global__ __launch_bounds__(256) void red_kernel(
    const float* __restrict__ zpart, const float* __restrict__ s0part,
    float* __restrict__ yG, float* __restrict__ S0G)
{
    __shared__ float redf[256];
    const int id = blockIdx.x;       // 0..63
    const int b = id >> 4, sl = id & 15;
    const int t = threadIdx.x;
    reduce_slice(b, sl, t, redf, zpart, yG);
    if (sl == 0 && t >= 64 && t < 128) {   // wave 1 reduces s0part for this batch
        const int tt = t - 64;
        float s0 = s0part[b*64 + tt];
        #pragma unroll
        for (int m = 1; m < 64; m <<= 1) s0 += __shfl_xor(s0, m);
        if (tt == 0) S0G[b] = s0;
    }
}

// ---------------- vl_gemm: out = tanh(rs*(xs@Wvl^T + bvl) + bl), rs fused via v_dot2 ----------------
__global__ __launch_bounds__(256, 2) void vl_gemm(const f16* __restrict__ A,
    const f16* __restrict__ Bt, const float* __restrict__ bvlG,
    const float* __restrict__ blG, const f16* __restrict__ uH,
    const float* __restrict__ c2G, const float* __restrict__ S0G,
    float* __restrict__ out)
{
    constexpr int K = 512;
    __shared__ f16 lA[128*32];
    __shared__ f16 lB[128*32];
    __shared__ float rsbuf[128];
    const int t = threadIdx.x;
    const int m0 = blockIdx.x*128, n0 = blockIdx.y*128;
    const int lane = t & 63, wid = t >> 6;
    const int wm = (wid & 1) << 6, wn = (wid >> 1) << 6;
    const int srow = t >> 2, skb = (t & 3) << 4;
    const long aoff0 = (long)(m0 + srow)*(K*2) + skb;
    const long aoff1 = aoff0 + 64L*(K*2);
    const long boff0 = (long)(n0 + srow)*(K*2) + skb;
    const long boff1 = boff0 + 64L*(K*2);
    char* ldsA = (char*)lA;
    char* ldsB = (char*)lB;
    const unsigned wbase = (unsigned)wid << 10;
    const char* Ab = (const char*)A;
    const char* Bb = (const char*)Bt;

    const int bat = blockIdx.x >> 5;          // 32 m-tiles per batch
    const f16* u = uH + bat*512;
    const int ku = (lane >> 4) << 3;

    f32x4 acc[4][4] = {};
    float racc[4] = {0.f,0.f,0.f,0.f};
    const int ael = (wm + (lane & 15))*32 + ku;
    const int bel = (wn + (lane & 15))*32 + ku;

    for (int k0 = 0; k0 < K; k0 += 32) {
        __syncthreads();
        const long kb = (long)k0*2;
        gl2lds16(Ab + aoff0 + kb, ldsA + wbase);
        gl2lds16(Ab + aoff1 + kb, ldsA + 4096 + wbase);
        gl2lds16(Bb + boff0 + kb, ldsB + wbase);
        gl2lds16(Bb + boff1 + kb, ldsB + 4096 + wbase);
        __syncthreads();
        f16x8 af[4], bf[4];
        #pragma unroll
        for (int i = 0; i < 4; i++) af[i] = *(const f16x8*)(lA + ael + i*512);
        #pragma unroll
        for (int j = 0; j < 4; j++) bf[j] = *(const f16x8*)(lB + bel + j*512);
        f16pack up; up.v8 = *(const f16x8*)(u + k0 + ku);
        #pragma unroll
        for (int i = 0; i < 4; i++) {
            f16pack ap; ap.v8 = af[i];
            #pragma unroll
            for (int q = 0; q < 4; q++)
                racc[i] = __builtin_amdgcn_fdot2(ap.v2[q], up.v2[q], racc[i], false);
        }
        #pragma unroll
        for (int i = 0; i < 4; i++)
            #pragma unroll
            for (int j = 0; j < 4; j++)
                acc[i][j] = __builtin_amdgcn_mfma_f32_16x16x32_f16(af[i], bf[j], acc[i][j], 0, 0, 0);
    }

    #pragma unroll
    for (int i = 0; i < 4; i++) {
        racc[i] += __shfl_xor(racc[i], 16);
        racc[i] += __shfl_xor(racc[i], 32);
    }
    const float S0 = S0G[bat], c2 = c2G[bat];
    if (wid < 2 && lane < 16) {
        #pragma unroll
        for (int i = 0; i < 4; i++)
            rsbuf[wm + i*16 + lane] = S0 + (racc[i] + c2)*(1.0f/512.0f);
    }
    __syncthreads();

    const int crb = m0 + wm + ((lane >> 4) << 2);
    const int ccb = n0 + wn + (lane & 15);
    const int lrb = wm + ((lane >> 4) << 2);
    #pragma unroll
    for (int i = 0; i < 4; i++) {
        float rsv[4];
        #pragma unroll
        for (int r = 0; r < 4; r++) rsv[r] = rsbuf[lrb + i*16 + r];
        #pragma unroll
        for (int j = 0; j < 4; j++) {
            int c = ccb + j*16;
            float bb = bvlG[c], bo = blG[c];
            #pragma unroll
            for (int r = 0; r < 4; r++) {
                float yv = rsv[r]*(acc[i][j][r] + bb) + bo;
                float e2 = __expf(2.0f*yv);
                out[(size_t)(crb + i*16 + r)*512 + c] = 1.0f - 2.0f/(e2 + 1.0f);
            }
        }
    }
}

extern "C" void kernel_launch(void* const* d_in, const int* in_sizes, int n_in,
                              void* d_out, int out_size, void* d_ws, size_t ws_size,
                              hipStream_t stream)
{
    const float* xs = (const float*)d_in[0];
    const float* Wk = (const float*)d_in[1];
    const float* bk = (const float*)d_in[2];
    const float* Wq = (const float*)d_in[3];
    const float* bq = (const float*)d_in[4];
    const float* Wv = (const float*)d_in[5];
    const float* bv = (const float*)d_in[6];
    const float* Wl = (const float*)d_in[7];
    const float* bl = (const float*)d_in[8];
    float* out = (float*)d_out;

    char* w = (char*)d_ws;
    f16*   xs_h = (f16*)w;   w += (size_t)M_*D_*2;   // 16.8 MB
    f16*   WvlH = (f16*)w;   w += (size_t)D_*D_*2;
    f16*   WlH  = (f16*)w;   w += (size_t)D_*D_*2;
    f16*   WvT  = (f16*)w;   w += (size_t)D_*D_*2;
    f16*   WkT  = (f16*)w;   w += (size_t)D_*D_*2;
    f16*   WqT  = (f16*)w;   w += (size_t)D_*D_*2;
    float* Mm   = (float*)w; w += (size_t)D_*D_*4;   // 1 MB
    float* MT   = (float*)w; w += (size_t)D_*D_*4;   // 1 MB
    float* xpart= (float*)w; w += (size_t)256*512*4; // 512 KB
    float* zpart= (float*)w; w += (size_t)256*512*4; // 512 KB
    float* s0part=(float*)w; w += (size_t)256*4;
    float* xsSum= (float*)w; w += (size_t)B_*D_*4;
    float* yG   = (float*)w; w += (size_t)B_*D_*4;
    float* hG   = (float*)w; w += (size_t)B_*D_*4;
    float* uG   = (float*)w; w += (size_t)B_*D_*4;
    f16*   uH   = (f16*)w;   w += (size_t)B_*D_*2;
    float* t1   = (float*)w; w += (size_t)D_*4;
    float* t2   = (float*)w; w += (size_t)D_*4;
    float* bvlG = (float*)w; w += (size_t)D_*4;
    float* S0G  = (float*)w; w += B_*4;
    float* c1G  = (float*)w; w += B_*4;
    float* c2G  = (float*)w; w += B_*4;
    float* t12  = (float*)w; w += 4;
    if ((size_t)(w - (char*)d_ws) > ws_size) return;  // fail loudly

    // no memset: no atomics anywhere; every buffer fully written by its producer

    prep_tr_kernel<<<512, 256, 0, stream>>>(xs, Wv, Wk, Wq, Wl,
        xs_h, xpart, WvT, WkT, WqT, WlH);

    wmm_kernel<<<dim3(8,8,4), 256, 0, stream>>>(WlH, WvT, WkT, WqT, Wl, bv, bk, bq,
        WvlH, bvlG, Mm, MT, t1, t2, t12, xpart, xsSum);

    mva_kernel<<<33, 256, 0, stream>>>(MT, xsSum, t1, t2, nullptr, t12, hG, nullptr, c1G);

    z_kernel<<<256, 256, 0, stream>>>(xs_h, hG, c1G, zpart, s0part);

    red_kernel<<<64, 256, 0, stream>>>(zpart, s0part, yG, S0G);

    mva_kernel<<<33, 256, 0, stream>>>(Mm, yG, t2, t1, S0G, t12, uG, uH, c2G);

    vl_gemm<<<dim3(128,4), 256, 0, stream>>>(xs_h, WvlH, bvlG, bl, uH, c2G, S0G, out);
}